// Round 1
// baseline (6357.317 us; speedup 1.0000x reference)
//
#include <hip/hip_runtime.h>
#include <math.h>

// ---------------------------------------------------------------------------
// SynchronAutoencoder: 3 stacked "synchron GRU" layers, W=512 units, C=16.
// Per layer: GRU0 (d_in=1) runs 512 sequential steps; then a chain of 15
// 2-step GRUs where only step-2's input matvec (y_prev @ kc[i]) is sequential.
// Strategy:
//   ka1: h1[i] (chain step-1 state)  -- parallel, reads kc (45 MB)
//   ka2: gh2[i] = h1[i]@rkc[i]+b_r   -- parallel, reads rkc (45 MB)
//   krc: persistent 64-WG kernel: 512 recurrent steps (rec weights LDS-
//        resident, 48KB/WG) + 15 chain steps (kc slice staged per step),
//        cross-WG h broadcast via agent-scope atomics + atomic-counter
//        grid barrier (64 WGs always co-resident on 256 CUs).
// ---------------------------------------------------------------------------

#define AGENT __HIP_MEMORY_SCOPE_AGENT
#define NWG   64
#define PADK  516   // 512 + 4 pad: breaks LDS bank alignment on stride-512 stores

__device__ __forceinline__ float agent_ld(const float* p) {
  return __hip_atomic_load((float*)p, __ATOMIC_RELAXED, AGENT);
}
__device__ __forceinline__ void agent_st(float* p, float v) {
  __hip_atomic_store(p, v, __ATOMIC_RELAXED, AGENT);
}
__device__ __forceinline__ float sigm(float x) { return 1.f / (1.f + __expf(-x)); }
__device__ __forceinline__ float tanh_f(float x) {
  // 1 - 2/(e^{2x}+1): no NaN at +/-inf, saturates correctly
  float e = __expf(2.f * x);
  return 1.f - 2.f / (e + 1.f);
}

// ---- KA1: chain step-1 hidden state h1[i][u], i<15, u<512 ------------------
// gx1 = x1 @ kc[i] + b_i ; gh1 = b_r (h0 = 0)
// z1=sig(gx1_z+b_r_z) r1=sig(gx1_r+b_r_r) hh1=tanh(gx1_h+r1*b_r_n); h1=(1-z1)*hh1
__global__ void ka1_kernel(const float* __restrict__ xin, const float* __restrict__ kc,
                           const float* __restrict__ bc, float* __restrict__ h1) {
  __shared__ float x1s[512];
  __shared__ float red[8][3][32];
  const int tid = threadIdx.x;
  x1s[tid]       = xin[tid * 16 + 1];
  x1s[tid + 256] = xin[(tid + 256) * 16 + 1];
  __syncthreads();
  const int i  = blockIdx.x >> 4;          // chain index 0..14
  const int ub = (blockIdx.x & 15) << 5;   // unit block of 32
  const int s = tid >> 5, c = tid & 31;
  const float* base = kc + (size_t)i * 786432 + ub + c;
  float a0 = 0.f, a1 = 0.f, a2 = 0.f;
  const int kk = s * 64;
  for (int k = kk; k < kk + 64; ++k) {
    const float xv = x1s[k];
    const float* row = base + (size_t)k * 1536;
    a0 = fmaf(xv, row[0],    a0);
    a1 = fmaf(xv, row[512],  a1);
    a2 = fmaf(xv, row[1024], a2);
  }
  red[s][0][c] = a0; red[s][1][c] = a1; red[s][2][c] = a2;
  __syncthreads();
  if (tid < 32) {
    const int u = tid;
    float g0 = 0.f, g1 = 0.f, g2 = 0.f;
    for (int ss = 0; ss < 8; ++ss) { g0 += red[ss][0][u]; g1 += red[ss][1][u]; g2 += red[ss][2][u]; }
    const float* bi = bc + (size_t)i * 3072;
    const float* br = bi + 1536;
    const int cz = ub + u, cr = 512 + ub + u, cn = 1024 + ub + u;
    const float z1  = sigm(g0 + bi[cz] + br[cz]);
    const float r1  = sigm(g1 + bi[cr] + br[cr]);
    const float hh1 = tanh_f(g2 + bi[cn] + r1 * br[cn]);
    h1[i * 512 + ub + u] = (1.f - z1) * hh1;
  }
}

// ---- KA2: gh2[i][col] = h1[i] @ rkc[i] + b_r[col] --------------------------
__global__ void ka2_kernel(const float* __restrict__ h1, const float* __restrict__ rkc,
                           const float* __restrict__ bc, float* __restrict__ gh2) {
  __shared__ float hs[512];
  __shared__ float red[4][64];
  const int tid = threadIdx.x;
  const int i  = blockIdx.x / 24;
  const int cb = (blockIdx.x % 24) << 6;   // col block of 64 (of 1536)
  hs[tid]       = h1[i * 512 + tid];
  hs[tid + 256] = h1[i * 512 + tid + 256];
  __syncthreads();
  const int s = tid >> 6, c = tid & 63;
  const float* base = rkc + (size_t)i * 786432 + cb + c;
  float acc = 0.f;
  const int kk = s * 128;
  for (int k = kk; k < kk + 128; ++k) acc = fmaf(hs[k], base[(size_t)k * 1536], acc);
  red[s][c] = acc;
  __syncthreads();
  if (tid < 64) {
    const float v = red[0][tid] + red[1][tid] + red[2][tid] + red[3][tid];
    gh2[i * 1536 + cb + tid] = v + bc[(size_t)i * 3072 + 1536 + cb + tid];
  }
}

// ---- KRC: persistent recurrent kernel (GRU0 512 steps + 15 chain steps) ----
// WG g owns units [g*8, g*8+8). 24 dots/step (8 units x 3 gates), one dot per
// wave per pass (3 passes, 8 waves). Weights transposed in LDS: wl[d][k],
// d = gate*8+u. Lane l covers k in {4l..4l+3} u {256+4l..256+4l+3}.
__global__ __launch_bounds__(512, 1) void krc_kernel(
    const float* __restrict__ xin, const float* __restrict__ k0,
    const float* __restrict__ rk0, const float* __restrict__ b0,
    const float* __restrict__ kc, const float* __restrict__ bc,
    const float* __restrict__ h1, const float* __restrict__ gh2,
    float* __restrict__ lout, float* hbuf, unsigned* cnt) {
  __shared__ __align__(16) float wl[24 * PADK];
  __shared__ __align__(16) float hl[512];
  __shared__ __align__(16) float x0l[512];
  __shared__ float dots[24];
  const int tid = threadIdx.x;
  const int g = blockIdx.x;
  const int gcol0 = g * 8;
  const int u8 = tid & 7, q = tid >> 3;
  const int wave = tid >> 6, lane = tid & 63;

  x0l[tid] = xin[tid * 16];                       // x0[t] = in[t*16 + 0]
  for (int idx = q; idx < 1536; idx += 64) {      // stage rk0 slice -> LDS
    const int k = idx & 511, gate = idx >> 9;
    wl[(gate * 8 + u8) * PADK + k] = rk0[(size_t)k * 1536 + gate * 512 + gcol0 + u8];
  }
  // gate-thread constants (lanes 0..7 of wave 0)
  float k0z = 0.f, k0r = 0.f, k0n = 0.f, biz = 0.f, bir = 0.f, bin_ = 0.f;
  float brz = 0.f, brr = 0.f, brn = 0.f;
  const int col = gcol0 + tid;  // valid for tid<8
  if (tid < 8) {
    k0z = k0[col];        k0r = k0[512 + col];  k0n = k0[1024 + col];
    biz = b0[col];        bir = b0[512 + col];  bin_ = b0[1024 + col];
    brz = b0[1536 + col]; brr = b0[2048 + col]; brn = b0[2560 + col];
  }

  unsigned target = 0;
  for (int s = 0; s < 512 + 15; ++s) {
    const bool chain = (s >= 512);
    const int ci = s - 512;
    float hv = 0.f;
    if (s != 0) hv = agent_ld(&hbuf[((s & 1) << 9) + tid]);  // read buf[s%2]
    if (chain) {                                             // stage kc[ci] slice
      const float* wsrc = kc + (size_t)ci * 786432;
      for (int idx = q; idx < 1536; idx += 64) {
        const int k = idx & 511, gate = idx >> 9;
        wl[(gate * 8 + u8) * PADK + k] = wsrc[(size_t)k * 1536 + gate * 512 + gcol0 + u8];
      }
    }
    hl[tid] = hv;
    __syncthreads();

    const float4 hA = *(const float4*)&hl[4 * lane];
    const float4 hB = *(const float4*)&hl[256 + 4 * lane];
#pragma unroll
    for (int p = 0; p < 3; ++p) {
      const int d = p * 8 + wave;
      const float* wp = &wl[d * PADK];
      const float4 wA = *(const float4*)&wp[4 * lane];
      const float4 wB = *(const float4*)&wp[256 + 4 * lane];
      float v = hA.x * wA.x + hA.y * wA.y + hA.z * wA.z + hA.w * wA.w +
                hB.x * wB.x + hB.y * wB.y + hB.z * wB.z + hB.w * wB.w;
      v += __shfl_xor(v, 1);  v += __shfl_xor(v, 2);  v += __shfl_xor(v, 4);
      v += __shfl_xor(v, 8);  v += __shfl_xor(v, 16); v += __shfl_xor(v, 32);
      if (lane == 0) dots[d] = v;
    }
    __syncthreads();

    if (tid < 8) {
      const float dz = dots[tid], dr = dots[8 + tid], dn = dots[16 + tid];
      float hnew;
      if (!chain) {
        const float xt = x0l[s];
        const float z  = sigm(fmaf(xt, k0z, biz) + dz + brz);
        const float r  = sigm(fmaf(xt, k0r, bir) + dr + brr);
        const float hh = tanh_f(fmaf(xt, k0n, bin_) + r * (dn + brn));
        const float hold = hl[col];
        hnew = z * hold + (1.f - z) * hh;
        if (s == 511) lout[col] = hnew;                       // y0
      } else {
        const float* bi = bc + (size_t)ci * 3072;
        const float* g2 = gh2 + ci * 1536;
        const float z  = sigm(dz + bi[col] + g2[col]);
        const float r  = sigm(dr + bi[512 + col] + g2[512 + col]);
        const float hh = tanh_f(dn + bi[1024 + col] + r * g2[1024 + col]);
        const float h1v = h1[ci * 512 + col];
        hnew = z * h1v + (1.f - z) * hh;
        lout[(ci + 1) * 512 + col] = hnew;                    // y_{ci+1}
      }
      agent_st(&hbuf[(((s + 1) & 1) << 9) + col], hnew);      // write buf[(s+1)%2]
    }

    // grid barrier: monotonic counter, one arrive per WG (wave 0 issued all
    // agent stores, so tid0's RELEASE covers them via per-wave vmcnt drain)
    target += NWG;
    if (tid == 0) {
      __hip_atomic_fetch_add(cnt, 1u, __ATOMIC_RELEASE, AGENT);
      while (__hip_atomic_load(cnt, __ATOMIC_ACQUIRE, AGENT) < target) {
        __builtin_amdgcn_s_sleep(2);
      }
    }
    __syncthreads();
  }
}

// ---------------------------------------------------------------------------
// d_ws layout: [0..256) barrier counters (zeroed each call via memsetAsync);
// floats after 256B: hbuf(1024) h1(7680) gh2(23040) lay1(8192) lay2(8192)
// total ~193 KB.
// ---------------------------------------------------------------------------
extern "C" void kernel_launch(void* const* d_in, const int* in_sizes, int n_in,
                              void* d_out, int out_size, void* d_ws, size_t ws_size,
                              hipStream_t stream) {
  (void)in_sizes; (void)n_in; (void)out_size; (void)ws_size;
  const float* x = (const float*)d_in[0];
  unsigned* cnt = (unsigned*)d_ws;
  float* F    = (float*)((char*)d_ws + 256);
  float* hbuf = F;            // 1024
  float* h1   = F + 1024;     // 15*512
  float* gh2  = F + 8704;     // 15*1536
  float* lay1 = F + 31744;    // 8192
  float* lay2 = F + 39936;    // 8192
  float* outf = (float*)d_out;

  hipMemsetAsync(d_ws, 0, 256, stream);   // barrier counters := 0 (ws is poisoned)

  const float* lin = x;
  float* louts[3] = {lay1, lay2, outf};
  for (int l = 0; l < 3; ++l) {
    const float* k0  = (const float*)d_in[1 + 6 * l + 0];
    const float* rk0 = (const float*)d_in[1 + 6 * l + 1];
    const float* b0  = (const float*)d_in[1 + 6 * l + 2];
    const float* kc  = (const float*)d_in[1 + 6 * l + 3];
    const float* rkc = (const float*)d_in[1 + 6 * l + 4];
    const float* bc  = (const float*)d_in[1 + 6 * l + 5];
    ka1_kernel<<<240, 256, 0, stream>>>(lin, kc, bc, h1);
    ka2_kernel<<<360, 256, 0, stream>>>(h1, rkc, bc, gh2);
    krc_kernel<<<NWG, 512, 0, stream>>>(lin, k0, rk0, b0, kc, bc, h1, gh2,
                                        louts[l], hbuf, cnt + l);
    lin = louts[l];
  }
}

// Round 3
// 4668.658 us; speedup vs baseline: 1.3617x; 1.3617x over previous
//
#include <hip/hip_runtime.h>
#include <math.h>

// ---------------------------------------------------------------------------
// SynchronAutoencoder: 3 stacked synchron-GRU layers, W=512, C=16.
// R3 = R2 with one fix: recurrent-phase poll read of the upper half of h
// used u64 offset 64+2l (float 128+4l) instead of 128+2l (float 256+4l),
// so dots consumed h[128..383] in place of h[256..511]. Window checks can't
// catch it (any slot holds a validly-encoded h) -> absmax 2.55e-2.
//
// Design recap: barrier-free persistent kernel. Producers publish h encoded
// as h+base (base alternates 2/8 by (step>>1)&1) into a ping-pong buffer;
// consumers poll the exact floats they need until in-window. Chain steps use
// row-slice partials (own y in registers, kc streamed coalesced) encoded
// with bases 4/16. WAR safety by induction through each WG's __syncthreads.
// ---------------------------------------------------------------------------

#define AGENT __HIP_MEMORY_SCOPE_AGENT
#define NWG   64

__device__ __forceinline__ float f32_ld(const float* p) {
  return __hip_atomic_load((float*)p, __ATOMIC_RELAXED, AGENT);
}
__device__ __forceinline__ void f32_st(float* p, float v) {
  __hip_atomic_store(p, v, __ATOMIC_RELAXED, AGENT);
}
__device__ __forceinline__ unsigned long long u64_ld(const unsigned long long* p) {
  return __hip_atomic_load((unsigned long long*)p, __ATOMIC_RELAXED, AGENT);
}
__device__ __forceinline__ float loF(unsigned long long u) {
  return __builtin_bit_cast(float, (unsigned)(u & 0xffffffffull));
}
__device__ __forceinline__ float hiF(unsigned long long u) {
  return __builtin_bit_cast(float, (unsigned)(u >> 32));
}
__device__ __forceinline__ float sigm(float x) { return 1.f / (1.f + __expf(-x)); }
__device__ __forceinline__ float tanh_f(float x) {
  float e = __expf(2.f * x);
  return 1.f - 2.f / (e + 1.f);
}

// ---- KA1: chain step-1 hidden state h1[i][u] (parallel, reads kc) ----------
__global__ void ka1_kernel(const float* __restrict__ xin, const float* __restrict__ kc,
                           const float* __restrict__ bc, float* __restrict__ h1) {
  __shared__ float x1s[512];
  __shared__ float red[8][3][32];
  const int tid = threadIdx.x;
  x1s[tid]       = xin[tid * 16 + 1];
  x1s[tid + 256] = xin[(tid + 256) * 16 + 1];
  __syncthreads();
  const int i  = blockIdx.x >> 4;          // chain index 0..14
  const int ub = (blockIdx.x & 15) << 5;   // unit block of 32
  const int s = tid >> 5, c = tid & 31;
  const float* base = kc + (size_t)i * 786432 + ub + c;
  float a0 = 0.f, a1 = 0.f, a2 = 0.f;
  const int kk = s * 64;
  for (int k = kk; k < kk + 64; ++k) {
    const float xv = x1s[k];
    const float* row = base + (size_t)k * 1536;
    a0 = fmaf(xv, row[0],    a0);
    a1 = fmaf(xv, row[512],  a1);
    a2 = fmaf(xv, row[1024], a2);
  }
  red[s][0][c] = a0; red[s][1][c] = a1; red[s][2][c] = a2;
  __syncthreads();
  if (tid < 32) {
    const int u = tid;
    float g0 = 0.f, g1 = 0.f, g2 = 0.f;
    for (int ss = 0; ss < 8; ++ss) { g0 += red[ss][0][u]; g1 += red[ss][1][u]; g2 += red[ss][2][u]; }
    const float* bi = bc + (size_t)i * 3072;
    const float* br = bi + 1536;
    const int cz = ub + u, cr = 512 + ub + u, cn = 1024 + ub + u;
    const float z1  = sigm(g0 + bi[cz] + br[cz]);
    const float r1  = sigm(g1 + bi[cr] + br[cr]);
    const float hh1 = tanh_f(g2 + bi[cn] + r1 * br[cn]);
    h1[i * 512 + ub + u] = (1.f - z1) * hh1;
  }
}

// ---- KA2: gh2[i][col] = h1[i] @ rkc[i] + b_r[col] (parallel, reads rkc) ----
__global__ void ka2_kernel(const float* __restrict__ h1, const float* __restrict__ rkc,
                           const float* __restrict__ bc, float* __restrict__ gh2) {
  __shared__ float hs[512];
  __shared__ float red[4][64];
  const int tid = threadIdx.x;
  const int i  = blockIdx.x / 24;
  const int cb = (blockIdx.x % 24) << 6;
  hs[tid]       = h1[i * 512 + tid];
  hs[tid + 256] = h1[i * 512 + tid + 256];
  __syncthreads();
  const int s = tid >> 6, c = tid & 63;
  const float* base = rkc + (size_t)i * 786432 + cb + c;
  float acc = 0.f;
  const int kk = s * 128;
  for (int k = kk; k < kk + 128; ++k) acc = fmaf(hs[k], base[(size_t)k * 1536], acc);
  red[s][c] = acc;
  __syncthreads();
  if (tid < 64) {
    const float v = red[0][tid] + red[1][tid] + red[2][tid] + red[3][tid];
    gh2[i * 1536 + cb + tid] = v + bc[(size_t)i * 3072 + 1536 + cb + tid];
  }
}

// ---- KRC: persistent, barrier-free recurrent kernel ------------------------
// WG g owns units [8g, 8g+8). Rec dot for (gate p, unit wave) computed by
// wave `wave`, pass p; weights live in 24 registers/thread (hoisted).
__global__ __launch_bounds__(512, 1) void krc_kernel(
    const float* __restrict__ xin, const float* __restrict__ k0,
    const float* __restrict__ rk0, const float* __restrict__ b0,
    const float* __restrict__ kc, const float* __restrict__ bc,
    const float* __restrict__ h1, const float* __restrict__ gh2,
    float* __restrict__ lout, float* hbuf, float* part) {
  __shared__ float x0l[512];
  __shared__ float ccon[15 * 56];   // per ci: bi_d[24], g2_d[24], h1v[8]
  __shared__ float dots[24];
  __shared__ float yl[8];
  const int tid  = threadIdx.x;
  const int g    = blockIdx.x;
  const int wave = tid >> 6, lane = tid & 63;
  const int col8 = g * 8;

  x0l[tid] = xin[tid * 16];
  for (int idx = tid; idx < 15 * 56; idx += 512) {
    const int ci = idx / 56, r = idx - ci * 56;
    float v;
    if (r < 24)      v = bc[(size_t)ci * 3072 + (r >> 3) * 512 + col8 + (r & 7)];
    else if (r < 48) v = gh2[ci * 1536 + ((r - 24) >> 3) * 512 + col8 + ((r - 24) & 7)];
    else             v = h1[ci * 512 + col8 + (r - 48)];
    ccon[idx] = v;
  }

  // Recurrent weight fragments (constant over all 512 steps): w[p][j] covers
  // k in {4*lane+j} u {256+4*lane+j} for column p*512 + col8 + wave.
  float w[3][8];
  {
    const int c0 = col8 + wave;
#pragma unroll
    for (int p = 0; p < 3; ++p) {
      const float* cp = rk0 + p * 512 + c0;
#pragma unroll
      for (int j = 0; j < 4; ++j) {
        w[p][j]     = cp[(size_t)(4 * lane + j) * 1536];
        w[p][4 + j] = cp[(size_t)(256 + 4 * lane + j) * 1536];
      }
    }
  }
  float k0z = 0.f, k0r = 0.f, k0n = 0.f, biz = 0.f, bir = 0.f, bin_ = 0.f;
  float brz = 0.f, brr = 0.f, brn = 0.f;
  const int col = col8 + tid;   // valid for tid<8
  if (tid < 8) {
    k0z = k0[col];        k0r = k0[512 + col];  k0n = k0[1024 + col];
    biz = b0[col];        bir = b0[512 + col];  bin_ = b0[1024 + col];
    brz = b0[1536 + col]; brr = b0[2048 + col]; brn = b0[2560 + col];
  }
  __syncthreads();

  // ---------------- recurrent phase: 512 steps ----------------
  float hprev = 0.f;                 // own-unit h, lanes 0-7 of wave 0
  for (int s = 0; s < 512; ++s) {
    float hA[8];
    if (s == 0) {
#pragma unroll
      for (int j = 0; j < 8; ++j) hA[j] = 0.f;
    } else {
      const float base = ((s >> 1) & 1) ? 8.f : 2.f;
      const unsigned long long* bp =
          (const unsigned long long*)(hbuf + ((s & 1) << 9));
      const unsigned long long* pa = bp + 2 * lane;          // floats 4l..4l+3
      const unsigned long long* pb = bp + 128 + 2 * lane;    // floats 256+4l.. (FIXED)
      bool ok;
      do {
        const unsigned long long a0 = u64_ld(pa), a1 = u64_ld(pa + 1);
        const unsigned long long b0v = u64_ld(pb), b1v = u64_ld(pb + 1);
        hA[0] = loF(a0);  hA[1] = hiF(a0);  hA[2] = loF(a1);  hA[3] = hiF(a1);
        hA[4] = loF(b0v); hA[5] = hiF(b0v); hA[6] = loF(b1v); hA[7] = hiF(b1v);
        ok = true;
#pragma unroll
        for (int j = 0; j < 8; ++j) ok = ok && (__builtin_fabsf(hA[j] - base) < 1.25f);
      } while (!__all(ok));
#pragma unroll
      for (int j = 0; j < 8; ++j) hA[j] -= base;
    }
#pragma unroll
    for (int p = 0; p < 3; ++p) {
      float v = 0.f;
#pragma unroll
      for (int j = 0; j < 8; ++j) v = fmaf(hA[j], w[p][j], v);
      v += __shfl_xor(v, 1);  v += __shfl_xor(v, 2);  v += __shfl_xor(v, 4);
      v += __shfl_xor(v, 8);  v += __shfl_xor(v, 16); v += __shfl_xor(v, 32);
      if (lane == 0) dots[p * 8 + wave] = v;
    }
    __syncthreads();
    if (tid < 8) {
      const float dz = dots[tid], dr = dots[8 + tid], dn = dots[16 + tid];
      const float xt = x0l[s];
      const float z  = sigm(fmaf(xt, k0z, biz) + dz + brz);
      const float r  = sigm(fmaf(xt, k0r, bir) + dr + brr);
      const float hh = tanh_f(fmaf(xt, k0n, bin_) + r * (dn + brn));
      const float hnew = z * hprev + (1.f - z) * hh;
      hprev = hnew;
      if (s < 511) {
        const float nb = (((s + 1) >> 1) & 1) ? 8.f : 2.f;
        f32_st(&hbuf[(((s + 1) & 1) << 9) + col], hnew + nb);
      } else {
        lout[col] = hnew;    // y0
        yl[tid]   = hnew;
      }
    }
  }
  __syncthreads();   // yl visible to whole WG

  // ---------------- chain phase: 15 steps ----------------
  // Row-slice partials: WG g uses ONLY its own y slice (yl) and its 8 kc
  // rows (coalesced). part[c][64] per column; reduce is coalesced 256B rows.
  for (int ci = 0; ci < 15; ++ci) {
    float y[8];
#pragma unroll
    for (int j = 0; j < 8; ++j) y[j] = yl[j];
    const float* kbase = kc + (size_t)ci * 786432 + (size_t)col8 * 1536 + tid;
    float a0 = 0.f, a1 = 0.f, a2 = 0.f;
#pragma unroll
    for (int j = 0; j < 8; ++j) {
      const float* row = kbase + (size_t)j * 1536;
      a0 = fmaf(y[j], row[0],    a0);
      a1 = fmaf(y[j], row[512],  a1);
      a2 = fmaf(y[j], row[1024], a2);
    }
    const float pb = ((ci >> 1) & 1) ? 16.f : 4.f;   // |partial| <= ~1.5 << 3
    float* pbuf = part + (size_t)(ci & 1) * (1536 * 64);
    f32_st(&pbuf[(size_t)tid * 64 + g],          a0 + pb);
    f32_st(&pbuf[(size_t)(tid + 512) * 64 + g],  a1 + pb);
    f32_st(&pbuf[(size_t)(tid + 1024) * 64 + g], a2 + pb);

    const float* r0 = &pbuf[(size_t)(col8 + wave) * 64 + lane];
    const float* r1 = &pbuf[(size_t)(512 + col8 + wave) * 64 + lane];
    const float* r2 = &pbuf[(size_t)(1024 + col8 + wave) * 64 + lane];
    float v0, v1, v2;
    bool ok;
    do {
      v0 = f32_ld(r0); v1 = f32_ld(r1); v2 = f32_ld(r2);
      ok = (__builtin_fabsf(v0 - pb) < 3.f) &&
           (__builtin_fabsf(v1 - pb) < 3.f) &&
           (__builtin_fabsf(v2 - pb) < 3.f);
    } while (!__all(ok));
    v0 -= pb; v1 -= pb; v2 -= pb;
    v0 += __shfl_xor(v0, 1);  v0 += __shfl_xor(v0, 2);  v0 += __shfl_xor(v0, 4);
    v0 += __shfl_xor(v0, 8);  v0 += __shfl_xor(v0, 16); v0 += __shfl_xor(v0, 32);
    v1 += __shfl_xor(v1, 1);  v1 += __shfl_xor(v1, 2);  v1 += __shfl_xor(v1, 4);
    v1 += __shfl_xor(v1, 8);  v1 += __shfl_xor(v1, 16); v1 += __shfl_xor(v1, 32);
    v2 += __shfl_xor(v2, 1);  v2 += __shfl_xor(v2, 2);  v2 += __shfl_xor(v2, 4);
    v2 += __shfl_xor(v2, 8);  v2 += __shfl_xor(v2, 16); v2 += __shfl_xor(v2, 32);
    if (lane == 0) { dots[wave] = v0; dots[8 + wave] = v1; dots[16 + wave] = v2; }
    __syncthreads();
    if (tid < 8) {
      const float* cc = &ccon[ci * 56];
      const float dz = dots[tid], dr = dots[8 + tid], dn = dots[16 + tid];
      const float z  = sigm(dz + cc[tid]      + cc[24 + tid]);
      const float r  = sigm(dr + cc[8 + tid]  + cc[32 + tid]);
      const float hh = tanh_f(dn + cc[16 + tid] + r * cc[40 + tid]);
      const float hnew = z * cc[48 + tid] + (1.f - z) * hh;
      lout[(ci + 1) * 512 + col] = hnew;
      yl[tid] = hnew;
    }
    __syncthreads();   // yl visible for next step's partials
  }
}

// ---------------------------------------------------------------------------
// d_ws layout (floats, per-layer regions to avoid cross-layer stale-valid
// aliasing of the encoded buffers):
//   hbuf:  3 * 1024                      @ 0
//   part:  3 * 2*1536*64 = 3*196608      @ 3072
//   h1:    15*512                        @ 592896
//   gh2:   15*1536                       @ 600576
//   lay1:  8192                          @ 623616
//   lay2:  8192                          @ 631808    (total ~2.56 MB)
// ---------------------------------------------------------------------------
extern "C" void kernel_launch(void* const* d_in, const int* in_sizes, int n_in,
                              void* d_out, int out_size, void* d_ws, size_t ws_size,
                              hipStream_t stream) {
  (void)in_sizes; (void)n_in; (void)out_size; (void)ws_size;
  const float* x = (const float*)d_in[0];
  float* F    = (float*)d_ws;
  float* hbuf = F;                 // 3*1024
  float* part = F + 3072;          // 3*196608
  float* h1   = F + 592896;        // 7680
  float* gh2  = F + 600576;        // 23040
  float* lay1 = F + 623616;        // 8192
  float* lay2 = F + 631808;        // 8192
  float* outf = (float*)d_out;

  const float* lin = x;
  float* louts[3] = {lay1, lay2, outf};
  for (int l = 0; l < 3; ++l) {
    const float* k0  = (const float*)d_in[1 + 6 * l + 0];
    const float* rk0 = (const float*)d_in[1 + 6 * l + 1];
    const float* b0  = (const float*)d_in[1 + 6 * l + 2];
    const float* kc  = (const float*)d_in[1 + 6 * l + 3];
    const float* rkc = (const float*)d_in[1 + 6 * l + 4];
    const float* bc  = (const float*)d_in[1 + 6 * l + 5];
    ka1_kernel<<<240, 256, 0, stream>>>(lin, kc, bc, h1);
    ka2_kernel<<<360, 256, 0, stream>>>(h1, rkc, bc, gh2);
    krc_kernel<<<NWG, 512, 0, stream>>>(lin, k0, rk0, b0, kc, bc, h1, gh2,
                                        louts[l], hbuf + l * 1024,
                                        part + (size_t)l * 393216);
    lin = louts[l];
  }
}